// Round 1
// baseline (59.088 us; speedup 1.0000x reference)
//
#include <hip/hip_runtime.h>

#define HOP      256
#define SAMPLES  262144
#define NBINS    513
#define NFRAMES  1024
#define FPB      16     // frames per block

// One block = 16 consecutive frames of one batch.
// 1024-pt real FFT per frame via 512-pt complex radix-2 DIF in LDS.
__global__ __launch_bounds__(256)
void stft_kernel(const float* __restrict__ x, const float* __restrict__ win,
                 float* __restrict__ out) {
  __shared__ float2 z[FPB * 512];  // exactly 64 KiB

  const int t   = threadIdx.x;
  const int b   = blockIdx.x >> 6;          // batch index (64 tiles per batch)
  const int f0  = (blockIdx.x & 63) * FPB;  // first frame of this tile
  const int f   = t & 15;                   // frame-lane for FFT/unpack phases
  const int sub = t >> 4;                   // 16 threads per frame

  // ---- load + window: natural order, XOR-f bank swizzle ----
  const float* xb = x + (size_t)b * SAMPLES;
  for (int ff = 0; ff < FPB; ++ff) {
    const int base = (f0 + ff) * HOP - 384;  // pad_left = 384
    float* zf = (float*)&z[ff * 512];
#pragma unroll
    for (int rep = 0; rep < 4; ++rep) {
      const int s = rep * 256 + t;
      const int idx = base + s;
      float v = (idx >= 0 && idx < SAMPLES) ? xb[idx] : 0.0f;
      v *= win[s];
      // z[ff][s>>1] component (s&1), column XOR-swizzled by ff
      zf[((s >> 1) ^ ff) * 2 + (s & 1)] = v;
    }
  }
  __syncthreads();

  // ---- 9 radix-2 DIF stages: natural input -> bit-reversed output ----
  // Each frame's 256 butterflies split across its 16 threads; lanes of a
  // wave span f=0..15 so the XOR-f swizzle spreads accesses over all banks.
  for (int st = 0; st < 9; ++st) {
    const int half = 256 >> st;
#pragma unroll
    for (int it = 0; it < 16; ++it) {
      const int bf = sub * 16 + it;          // butterfly index 0..255
      const int j  = bf & (half - 1);
      const int i0 = ((bf >> (8 - st)) << (9 - st)) | j;
      const int i1 = i0 + half;
      // w = exp(-2*pi*i * j / (512>>st)) ; (j<<st) in [0,255]
      float sn, cs;
      __sincosf((float)(j << st) * (-3.14159265358979323846f / 256.0f), &sn, &cs);
      float2 a = z[f * 512 + (i0 ^ f)];
      float2 c = z[f * 512 + (i1 ^ f)];
      float2 d0; d0.x = a.x + c.x;           d0.y = a.y + c.y;
      float2 d1; d1.x = a.x - c.x;           d1.y = a.y - c.y;
      float2 e1; e1.x = d1.x * cs - d1.y * sn; e1.y = d1.x * sn + d1.y * cs;
      z[f * 512 + (i0 ^ f)] = d0;
      z[f * 512 + (i1 ^ f)] = e1;
    }
    __syncthreads();
  }

  // ---- real-FFT unpack + transposed coalesced write ----
  // Z[k] sits at bit-reversed position rev9(k).
  float* out_r = out;
  float* out_i = out + (size_t)16 * NBINS * NFRAMES;
  const int fr = f0 + f;
  for (int k = sub; k <= 512; k += 16) {
    const int pk = __brev((unsigned)(k & 511)) >> 23;
    const int pm = __brev((unsigned)((512 - k) & 511)) >> 23;
    float2 Zk = z[f * 512 + (pk ^ f)];
    float2 Zm = z[f * 512 + (pm ^ f)];
    // Xe = (Zk + conj(Zm))/2 ; Xo = (Zk - conj(Zm))/(2i)
    float xer  = 0.5f * (Zk.x + Zm.x);
    float xei  = 0.5f * (Zk.y - Zm.y);
    float xo_r = 0.5f * (Zk.y + Zm.y);
    float xo_i = -0.5f * (Zk.x - Zm.x);
    // tw = exp(-2*pi*i*k/1024)
    float sn, cs;
    __sincosf((float)k * (-6.28318530717958647693f / 1024.0f), &sn, &cs);
    float xr = xer + cs * xo_r - sn * xo_i;
    float xi = xei + cs * xo_i + sn * xo_r;
    size_t o = ((size_t)b * NBINS + k) * NFRAMES + fr;
    out_r[o] = xr;   // 16 lanes (f=0..15) -> 64B contiguous segment
    out_i[o] = xi;
  }
}

extern "C" void kernel_launch(void* const* d_in, const int* in_sizes, int n_in,
                              void* d_out, int out_size, void* d_ws, size_t ws_size,
                              hipStream_t stream) {
  const float* x = (const float*)d_in[0];
  const float* w = (const float*)d_in[1];
  float* out = (float*)d_out;
  (void)in_sizes; (void)n_in; (void)out_size; (void)d_ws; (void)ws_size;
  stft_kernel<<<dim3(1024), dim3(256), 0, stream>>>(x, w, out);
}

// Round 2
// 28.296 us; speedup vs baseline: 2.0882x; 2.0882x over previous
//
#include <hip/hip_runtime.h>

#define HOP      256
#define SAMPLES  262144
#define NBINS    513
#define NFRAMES  1024
#define FPB      16   // frames per block, one wave per frame

__device__ __forceinline__ float2 cmul(float2 a, float2 b) {
  return make_float2(a.x * b.x - a.y * b.y, a.x * b.y + a.y * b.x);
}

// 8-point DFT, natural-order in (index n) and out (index k), W = e^{-2pi i/8}
__device__ __forceinline__ void fft8(float2 v[8]) {
  const float R = 0.70710678118654752440f;
  float2 s0 = make_float2(v[0].x + v[4].x, v[0].y + v[4].y);
  float2 d0 = make_float2(v[0].x - v[4].x, v[0].y - v[4].y);
  float2 s1 = make_float2(v[1].x + v[5].x, v[1].y + v[5].y);
  float2 d1 = make_float2(v[1].x - v[5].x, v[1].y - v[5].y);
  float2 s2 = make_float2(v[2].x + v[6].x, v[2].y + v[6].y);
  float2 d2 = make_float2(v[2].x - v[6].x, v[2].y - v[6].y);
  float2 s3 = make_float2(v[3].x + v[7].x, v[3].y + v[7].y);
  float2 d3 = make_float2(v[3].x - v[7].x, v[3].y - v[7].y);
  // twiddles W8^1, W8^2, W8^3 on the d-branch
  float2 e1 = make_float2(R * (d1.x + d1.y), R * (d1.y - d1.x));
  float2 e2 = make_float2(d2.y, -d2.x);
  float2 e3 = make_float2(R * (d3.y - d3.x), R * (-d3.x - d3.y));
  // 4-pt on s-branch -> even outputs
  float2 p0 = make_float2(s0.x + s2.x, s0.y + s2.y);
  float2 q0 = make_float2(s0.x - s2.x, s0.y - s2.y);
  float2 p1 = make_float2(s1.x + s3.x, s1.y + s3.y);
  float2 q1 = make_float2(s1.x - s3.x, s1.y - s3.y);
  float2 q1t = make_float2(q1.y, -q1.x);
  // 4-pt on d-branch -> odd outputs
  float2 p2 = make_float2(d0.x + e2.x, d0.y + e2.y);
  float2 q2 = make_float2(d0.x - e2.x, d0.y - e2.y);
  float2 p3 = make_float2(e1.x + e3.x, e1.y + e3.y);
  float2 q3 = make_float2(e1.x - e3.x, e1.y - e3.y);
  float2 q3t = make_float2(q3.y, -q3.x);
  v[0] = make_float2(p0.x + p1.x, p0.y + p1.y);
  v[4] = make_float2(p0.x - p1.x, p0.y - p1.y);
  v[2] = make_float2(q0.x + q1t.x, q0.y + q1t.y);
  v[6] = make_float2(q0.x - q1t.x, q0.y - q1t.y);
  v[1] = make_float2(p2.x + p3.x, p2.y + p3.y);
  v[5] = make_float2(p2.x - p3.x, p2.y - p3.y);
  v[3] = make_float2(q2.x + q3t.x, q2.y + q3t.y);
  v[7] = make_float2(q2.x - q3t.x, q2.y - q3t.y);
}

// bank-conflict-free swizzle: c = (H<<6)|(M<<3)|L  ->  (H<<6)|((M^(H&1))<<3)|(L^M)
__device__ __forceinline__ int swz(int c) {
  int H = c >> 6, M = (c >> 3) & 7, L = c & 7;
  return (H << 6) | ((M ^ (H & 1)) << 3) | (L ^ M);
}

__global__ __launch_bounds__(1024)
void stft_kernel(const float* __restrict__ x, const float* __restrict__ win,
                 float* __restrict__ out) {
  __shared__ float2 z[FPB * 512];  // 64 KiB
  const int t  = threadIdx.x;
  const int b  = blockIdx.x >> 6;
  const int f0 = (blockIdx.x & 63) * FPB;

  // ---------------- FFT phase: one wave per frame, all LDS intra-wave ------
  {
    const int w = t >> 6;   // wave = frame-in-tile
    const int u = t & 63;   // lane = n2
    const int fr = f0 + w;
    const float* xb = x + (size_t)b * SAMPLES;
    const int base = fr * HOP - 384;  // pad_left = 384
    float2* zf = z + w * 512;

    // load 8 complex (pairs of real samples), window, registers
    float2 r[8];
#pragma unroll
    for (int n1 = 0; n1 < 8; ++n1) {
      int s = 2 * (64 * n1 + u);
      int idx = base + s;
      float2 xv = make_float2(0.f, 0.f);
      if (idx >= 0 && idx < SAMPLES) xv = *(const float2*)(xb + idx);
      float2 wv = *(const float2*)(win + s);
      r[n1] = make_float2(xv.x * wv.x, xv.y * wv.y);
    }

    // stage 1: radix-8 over n1 (stride 64), twiddle W512^{u*k1}
    fft8(r);
    float sn, cs;
    __sincosf((float)u * (-6.28318530717958647693f / 512.f), &sn, &cs);
    float2 wb = make_float2(cs, sn), tw = wb;
#pragma unroll
    for (int k1 = 1; k1 < 8; ++k1) {
      r[k1] = cmul(r[k1], tw);
      if (k1 < 7) tw = cmul(tw, wb);
    }
    // exchange 1 write: c = 64*k1 + u
#pragma unroll
    for (int k1 = 0; k1 < 8; ++k1) zf[swz((k1 << 6) | u) ^ w] = r[k1];

    // exchange 1 read: (g = u>>3, m2 = u&7), c = 64g + 8*m1 + m2
    const int g = u >> 3, m2 = u & 7;
    float2 y[8];
#pragma unroll
    for (int m1 = 0; m1 < 8; ++m1) y[m1] = zf[swz((g << 6) | (m1 << 3) | m2) ^ w];

    // stage 2: radix-8 over m1, twiddle W64^{m2*j1}
    fft8(y);
    __sincosf((float)m2 * (-6.28318530717958647693f / 64.f), &sn, &cs);
    wb = make_float2(cs, sn); tw = wb;
#pragma unroll
    for (int j1 = 1; j1 < 8; ++j1) {
      y[j1] = cmul(y[j1], tw);
      if (j1 < 7) tw = cmul(tw, wb);
    }
    // exchange 2 write: c = 64g + 8*j1 + m2   (layout [g][j1][m2])
#pragma unroll
    for (int j1 = 0; j1 < 8; ++j1) zf[swz((g << 6) | (j1 << 3) | m2) ^ w] = y[j1];

    // exchange 2 read: (g, j1 = u&7), c = 64g + 8*j1 + m  over m
    const int j1 = u & 7;
    float2 h[8];
#pragma unroll
    for (int m = 0; m < 8; ++m) h[m] = zf[swz((g << 6) | (j1 << 3) | m) ^ w];

    // stage 3: radix-8 over m2 -> j2; store Z[k] natural order, k = g+8j1+64j2
    fft8(h);
#pragma unroll
    for (int j2 = 0; j2 < 8; ++j2) zf[swz(g | (j1 << 3) | (j2 << 6)) ^ w] = h[j2];
  }
  __syncthreads();

  // ---------------- unpack + transposed coalesced write --------------------
  {
    const int f  = t & 15;   // frame-in-tile (lane-fastest -> 64B segments)
    const int q  = t >> 4;   // bin group
    const int fr = f0 + f;
    const float2* zf = z + f * 512;
    float* out_r = out;
    float* out_i = out + (size_t)16 * NBINS * NFRAMES;
    float sn, cs;
    __sincosf((float)q * (-6.28318530717958647693f / 1024.f), &sn, &cs);
    float2 tw = make_float2(cs, sn);
    const float2 stp = make_float2(0.92387953251128675613f, -0.38268343236508977173f);
#pragma unroll
    for (int i = 0; i < 9; ++i) {
      int k = q + (i << 6);
      if (k > 512) break;
      float2 Zk = zf[swz(k & 511) ^ f];
      float2 Zm = zf[swz((512 - k) & 511) ^ f];
      float xer  = 0.5f * (Zk.x + Zm.x);
      float xei  = 0.5f * (Zk.y - Zm.y);
      float xor_ = 0.5f * (Zk.y + Zm.y);
      float xoi  = -0.5f * (Zk.x - Zm.x);
      float xr = xer + tw.x * xor_ - tw.y * xoi;
      float xi = xei + tw.x * xoi + tw.y * xor_;
      size_t o = ((size_t)b * NBINS + k) * NFRAMES + fr;
      out_r[o] = xr;
      out_i[o] = xi;
      tw = cmul(tw, stp);
    }
  }
}

extern "C" void kernel_launch(void* const* d_in, const int* in_sizes, int n_in,
                              void* d_out, int out_size, void* d_ws, size_t ws_size,
                              hipStream_t stream) {
  const float* x = (const float*)d_in[0];
  const float* w = (const float*)d_in[1];
  float* out = (float*)d_out;
  (void)in_sizes; (void)n_in; (void)out_size; (void)d_ws; (void)ws_size;
  stft_kernel<<<dim3(1024), dim3(1024), 0, stream>>>(x, w, out);
}

// Round 4
// 27.716 us; speedup vs baseline: 2.1319x; 1.0209x over previous
//
#include <hip/hip_runtime.h>

#define HOP      256
#define SAMPLES  262144
#define NBINS    513
#define NFRAMES  1024
#define FPB      16   // frames per block, one wave per frame

__device__ __forceinline__ float2 cmul(float2 a, float2 b) {
  return make_float2(a.x * b.x - a.y * b.y, a.x * b.y + a.y * b.x);
}

// 8-point DFT, natural-order in (index n) and out (index k), W = e^{-2pi i/8}
__device__ __forceinline__ void fft8(float2 v[8]) {
  const float R = 0.70710678118654752440f;
  float2 s0 = make_float2(v[0].x + v[4].x, v[0].y + v[4].y);
  float2 d0 = make_float2(v[0].x - v[4].x, v[0].y - v[4].y);
  float2 s1 = make_float2(v[1].x + v[5].x, v[1].y + v[5].y);
  float2 d1 = make_float2(v[1].x - v[5].x, v[1].y - v[5].y);
  float2 s2 = make_float2(v[2].x + v[6].x, v[2].y + v[6].y);
  float2 d2 = make_float2(v[2].x - v[6].x, v[2].y - v[6].y);
  float2 s3 = make_float2(v[3].x + v[7].x, v[3].y + v[7].y);
  float2 d3 = make_float2(v[3].x - v[7].x, v[3].y - v[7].y);
  float2 e1 = make_float2(R * (d1.x + d1.y), R * (d1.y - d1.x));
  float2 e2 = make_float2(d2.y, -d2.x);
  float2 e3 = make_float2(R * (d3.y - d3.x), R * (-d3.x - d3.y));
  float2 p0 = make_float2(s0.x + s2.x, s0.y + s2.y);
  float2 q0 = make_float2(s0.x - s2.x, s0.y - s2.y);
  float2 p1 = make_float2(s1.x + s3.x, s1.y + s3.y);
  float2 q1 = make_float2(s1.x - s3.x, s1.y - s3.y);
  float2 q1t = make_float2(q1.y, -q1.x);
  float2 p2 = make_float2(d0.x + e2.x, d0.y + e2.y);
  float2 q2 = make_float2(d0.x - e2.x, d0.y - e2.y);
  float2 p3 = make_float2(e1.x + e3.x, e1.y + e3.y);
  float2 q3 = make_float2(e1.x - e3.x, e1.y - e3.y);
  float2 q3t = make_float2(q3.y, -q3.x);
  v[0] = make_float2(p0.x + p1.x, p0.y + p1.y);
  v[4] = make_float2(p0.x - p1.x, p0.y - p1.y);
  v[2] = make_float2(q0.x + q1t.x, q0.y + q1t.y);
  v[6] = make_float2(q0.x - q1t.x, q0.y - q1t.y);
  v[1] = make_float2(p2.x + p3.x, p2.y + p3.y);
  v[5] = make_float2(p2.x - p3.x, p2.y - p3.y);
  v[3] = make_float2(q2.x + q3t.x, q2.y + q3t.y);
  v[7] = make_float2(q2.x - q3t.x, q2.y - q3t.y);
}

// bank-conflict-free swizzle: c = (H<<6)|(M<<3)|L -> (H<<6)|((M^(H&1))<<3)|(L^M)
__device__ __forceinline__ int swz(int c) {
  int H = c >> 6, M = (c >> 3) & 7, L = c & 7;
  return (H << 6) | ((M ^ (H & 1)) << 3) | (L ^ M);
}

__global__ __launch_bounds__(1024, 8)   // force VGPR<=64 -> 2 blocks/CU
void stft_kernel(const float* __restrict__ x, const float* __restrict__ win,
                 float* __restrict__ out) {
  __shared__ float2 z[FPB * 512];  // 64 KiB
  const int t  = threadIdx.x;
  const int b  = blockIdx.x >> 6;
  const int f0 = (blockIdx.x & 63) * FPB;

  // ---------------- FFT phase: one wave per frame, all LDS intra-wave ------
  {
    const int w = t >> 6;   // wave = frame-in-tile
    const int u = t & 63;   // lane = n2
    const int fr = f0 + w;
    const float* xb = x + (size_t)b * SAMPLES;
    const int base = fr * HOP - 384;  // pad_left = 384
    float2* zf = z + w * 512;

    // load 8 complex (pairs of real samples), window, registers
    float2 r[8];
#pragma unroll
    for (int n1 = 0; n1 < 8; ++n1) {
      int s = 2 * (64 * n1 + u);
      int idx = base + s;
      float2 xv = make_float2(0.f, 0.f);
      if (idx >= 0 && idx < SAMPLES) xv = *(const float2*)(xb + idx);
      float2 wv = *(const float2*)(win + s);
      r[n1] = make_float2(xv.x * wv.x, xv.y * wv.y);
    }

    // stage 1: radix-8 over n1 (stride 64), twiddle W512^{u*k1}
    fft8(r);
    float sn, cs;
    __sincosf((float)u * (-6.28318530717958647693f / 512.f), &sn, &cs);
    {
      float2 w1 = make_float2(cs, sn);
      float2 w2 = cmul(w1, w1);
      float2 w3 = cmul(w2, w1);
      float2 w4 = cmul(w2, w2);
      r[1] = cmul(r[1], w1);
      r[2] = cmul(r[2], w2);
      r[3] = cmul(r[3], w3);
      r[4] = cmul(r[4], w4);
      r[5] = cmul(r[5], cmul(w4, w1));
      r[6] = cmul(r[6], cmul(w4, w2));
      r[7] = cmul(r[7], cmul(w4, w3));
    }
#pragma unroll
    for (int k1 = 0; k1 < 8; ++k1) zf[swz((k1 << 6) | u) ^ w] = r[k1];

    // exchange 1 read: (g = u>>3, m2 = u&7), c = 64g + 8*m1 + m2
    const int g = u >> 3, m2 = u & 7;
    float2 y[8];
#pragma unroll
    for (int m1 = 0; m1 < 8; ++m1) y[m1] = zf[swz((g << 6) | (m1 << 3) | m2) ^ w];

    // stage 2: radix-8 over m1, twiddle W64^{m2*j1}
    fft8(y);
    __sincosf((float)m2 * (-6.28318530717958647693f / 64.f), &sn, &cs);
    {
      float2 w1 = make_float2(cs, sn);
      float2 w2 = cmul(w1, w1);
      float2 w3 = cmul(w2, w1);
      float2 w4 = cmul(w2, w2);
      y[1] = cmul(y[1], w1);
      y[2] = cmul(y[2], w2);
      y[3] = cmul(y[3], w3);
      y[4] = cmul(y[4], w4);
      y[5] = cmul(y[5], cmul(w4, w1));
      y[6] = cmul(y[6], cmul(w4, w2));
      y[7] = cmul(y[7], cmul(w4, w3));
    }
#pragma unroll
    for (int j1 = 0; j1 < 8; ++j1) zf[swz((g << 6) | (j1 << 3) | m2) ^ w] = y[j1];

    // exchange 2 read: (g, j1 = u&7), c = 64g + 8*j1 + m over m
    const int j1 = u & 7;
    float2 h[8];
#pragma unroll
    for (int m = 0; m < 8; ++m) h[m] = zf[swz((g << 6) | (j1 << 3) | m) ^ w];

    // stage 3: radix-8 over m2 -> j2; store Z[k] natural order, k = g+8j1+64j2
    fft8(h);
#pragma unroll
    for (int j2 = 0; j2 < 8; ++j2) zf[swz(g | (j1 << 3) | (j2 << 6)) ^ w] = h[j2];
  }
  __syncthreads();

  // -------- unpack via conjugate symmetry + transposed coalesced write -----
  // From (Z[k], Z[512-k]) compute BOTH X[k] = Xe + W^k Xo and
  // X[512-k] = conj(Xe - W^k Xo).  Covers k=0..256 directly, 256..512 mirrored.
  {
    const int f  = t & 15;   // frame-in-tile (lane-fastest -> 64B segments)
    const int q  = t >> 4;   // bin residue 0..63
    const int fr = f0 + f;
    const float2* zf = z + f * 512;
    float* out_r = out;
    float* out_i = out + (size_t)16 * NBINS * NFRAMES;
    float sn, cs;
    __sincosf((float)q * (-6.28318530717958647693f / 1024.f), &sn, &cs);
    float2 tw = make_float2(cs, sn);
    // bin step is 64: stp = W_1024^64 = e^{-i*pi/8}  (round-3 bug: had W^32)
    const float2 stp = make_float2(0.92387953251128675613f, -0.38268343236508977173f);
#pragma unroll
    for (int i = 0; i < 5; ++i) {
      int k = q + (i << 6);
      if (k > 256) break;
      float2 Zk = zf[swz(k) ^ f];
      float2 Zm = zf[swz((512 - k) & 511) ^ f];
      float xer  = 0.5f * (Zk.x + Zm.x);
      float xei  = 0.5f * (Zk.y - Zm.y);
      float xor_ = 0.5f * (Zk.y + Zm.y);
      float xoi  = -0.5f * (Zk.x - Zm.x);
      float ur = tw.x * xor_ - tw.y * xoi;
      float ui = tw.x * xoi + tw.y * xor_;
      size_t o1 = ((size_t)b * NBINS + k) * NFRAMES + fr;
      size_t o2 = ((size_t)b * NBINS + (512 - k)) * NFRAMES + fr;
      out_r[o1] = xer + ur;
      out_i[o1] = xei + ui;
      out_r[o2] = xer - ur;
      out_i[o2] = ui - xei;
      tw = cmul(tw, stp);
    }
  }
}

extern "C" void kernel_launch(void* const* d_in, const int* in_sizes, int n_in,
                              void* d_out, int out_size, void* d_ws, size_t ws_size,
                              hipStream_t stream) {
  const float* x = (const float*)d_in[0];
  const float* w = (const float*)d_in[1];
  float* out = (float*)d_out;
  (void)in_sizes; (void)n_in; (void)out_size; (void)d_ws; (void)ws_size;
  stft_kernel<<<dim3(1024), dim3(1024), 0, stream>>>(x, w, out);
}

// Round 5
// 24.557 us; speedup vs baseline: 2.4061x; 1.1286x over previous
//
#include <hip/hip_runtime.h>

#define HOP      256
#define SAMPLES  262144
#define NBINS    513
#define NFRAMES  1024
#define FPB      16   // frames per block, one wave per frame

__device__ __forceinline__ float2 cmul(float2 a, float2 b) {
  return make_float2(a.x * b.x - a.y * b.y, a.x * b.y + a.y * b.x);
}

__device__ __forceinline__ float2 lds_ld(const float2* p, int bo) {
  return *(const float2*)((const char*)p + bo);
}
__device__ __forceinline__ void lds_st(float2* p, int bo, float2 v) {
  *(float2*)((char*)p + bo) = v;
}

// original swizzle (kept for the unpack mirror read):
// c = (H<<6)|(M<<3)|L -> (H<<6)|((M^(H&1))<<3)|(L^M)
__device__ __forceinline__ int swz(int c) {
  int H = c >> 6, M = (c >> 3) & 7, L = c & 7;
  return (H << 6) | ((M ^ (H & 1)) << 3) | (L ^ M);
}

// 8-point DFT, natural-order in/out, W = e^{-2pi i/8}
__device__ __forceinline__ void fft8(float2 v[8]) {
  const float R = 0.70710678118654752440f;
  float2 s0 = make_float2(v[0].x + v[4].x, v[0].y + v[4].y);
  float2 d0 = make_float2(v[0].x - v[4].x, v[0].y - v[4].y);
  float2 s1 = make_float2(v[1].x + v[5].x, v[1].y + v[5].y);
  float2 d1 = make_float2(v[1].x - v[5].x, v[1].y - v[5].y);
  float2 s2 = make_float2(v[2].x + v[6].x, v[2].y + v[6].y);
  float2 d2 = make_float2(v[2].x - v[6].x, v[2].y - v[6].y);
  float2 s3 = make_float2(v[3].x + v[7].x, v[3].y + v[7].y);
  float2 d3 = make_float2(v[3].x - v[7].x, v[3].y - v[7].y);
  float2 e1 = make_float2(R * (d1.x + d1.y), R * (d1.y - d1.x));
  float2 e2 = make_float2(d2.y, -d2.x);
  float2 e3 = make_float2(R * (d3.y - d3.x), R * (-d3.x - d3.y));
  float2 p0 = make_float2(s0.x + s2.x, s0.y + s2.y);
  float2 q0 = make_float2(s0.x - s2.x, s0.y - s2.y);
  float2 p1 = make_float2(s1.x + s3.x, s1.y + s3.y);
  float2 q1 = make_float2(s1.x - s3.x, s1.y - s3.y);
  float2 q1t = make_float2(q1.y, -q1.x);
  float2 p2 = make_float2(d0.x + e2.x, d0.y + e2.y);
  float2 q2 = make_float2(d0.x - e2.x, d0.y - e2.y);
  float2 p3 = make_float2(e1.x + e3.x, e1.y + e3.y);
  float2 q3 = make_float2(e1.x - e3.x, e1.y - e3.y);
  float2 q3t = make_float2(q3.y, -q3.x);
  v[0] = make_float2(p0.x + p1.x, p0.y + p1.y);
  v[4] = make_float2(p0.x - p1.x, p0.y - p1.y);
  v[2] = make_float2(q0.x + q1t.x, q0.y + q1t.y);
  v[6] = make_float2(q0.x - q1t.x, q0.y - q1t.y);
  v[1] = make_float2(p2.x + p3.x, p2.y + p3.y);
  v[5] = make_float2(p2.x - p3.x, p2.y - p3.y);
  v[3] = make_float2(q2.x + q3t.x, q2.y + q3t.y);
  v[7] = make_float2(q2.x - q3t.x, q2.y - q3t.y);
}

__global__ __launch_bounds__(1024, 8)   // VGPR<=64 -> 2 blocks/CU
void stft_kernel(const float* __restrict__ x, const float* __restrict__ win,
                 float* __restrict__ out) {
  __shared__ float2 z[FPB * 512];  // 64 KiB
  const int t  = threadIdx.x;
  const int b  = blockIdx.x >> 6;
  const int f0 = (blockIdx.x & 63) * FPB;

  // ---------------- FFT phase: one wave per frame, all LDS intra-wave ------
  {
    const int w = t >> 6;     // wave = frame-in-tile
    const int u = t & 63;     // lane
    const int g = u >> 3, m2l = u & 7;
    float2* zf = z + (w << 9);

    // closed-form swizzled addresses (bytes), derived from swz():
    const int A0    = (g << 3) | (m2l ^ g);
    const int B1w_e = (A0 ^ w) << 3;                              // ex1 write, even k1
    const int B1w_o = B1w_e ^ 64;                                 //            odd k1
    const int C1    = (g << 6) | ((g & 1) << 3) | m2l;
    const int B1r   = (C1 ^ w) << 3;   // ex1 read / ex2 write: ^ (72*m1)
    const int D0    = (g << 6) | ((m2l ^ (g & 1)) << 3) | m2l;
    const int B2r   = (D0 ^ w) << 3;   // ex2 read: ^ (m<<3)
    const int F0    = (m2l << 3) | (g ^ m2l);
    const int B3_e  = (F0 ^ w) << 3;                              // st3 write, even j2
    const int B3_o  = B3_e ^ 64;                                  //            odd j2

    // ---- load + window (bounds check only in first/last tile) ----
    const float* xb = x + (size_t)b * SAMPLES;
    const int fr   = f0 + w;
    const int base = fr * HOP - 384;  // pad_left = 384
    float2 r[8];
    if (f0 != 0 && f0 != (NFRAMES - FPB)) {
      const float2* xc = (const float2*)(xb + base);
      const float2* wc = (const float2*)win;
#pragma unroll
      for (int n1 = 0; n1 < 8; ++n1) {
        float2 xv = xc[(n1 << 6) + u];
        float2 wv = wc[(n1 << 6) + u];
        r[n1] = make_float2(xv.x * wv.x, xv.y * wv.y);
      }
    } else {
#pragma unroll
      for (int n1 = 0; n1 < 8; ++n1) {
        int s = (n1 << 7) + 2 * u;
        int idx = base + s;
        float2 xv = make_float2(0.f, 0.f);
        if (idx >= 0 && idx < SAMPLES) xv = *(const float2*)(xb + idx);
        float2 wv = *(const float2*)(win + s);
        r[n1] = make_float2(xv.x * wv.x, xv.y * wv.y);
      }
    }

    // ---- stage 1: radix-8, twiddle W512^{u*k1} ----
    fft8(r);
    float sn, cs;
    __sincosf((float)u * (-6.28318530717958647693f / 512.f), &sn, &cs);
    {
      float2 w1 = make_float2(cs, sn);
      float2 w2 = cmul(w1, w1);
      float2 w3 = cmul(w2, w1);
      float2 w4 = cmul(w2, w2);
      r[1] = cmul(r[1], w1);
      r[2] = cmul(r[2], w2);
      r[3] = cmul(r[3], w3);
      r[4] = cmul(r[4], w4);
      r[5] = cmul(r[5], cmul(w4, w1));
      r[6] = cmul(r[6], cmul(w4, w2));
      r[7] = cmul(r[7], cmul(w4, w3));
    }
    // ex1 write: addr = base_even/odd + k1*512 (ds imm offsets)
    lds_st(zf, B1w_e,        r[0]);
    lds_st(zf, B1w_o +  512, r[1]);
    lds_st(zf, B1w_e + 1024, r[2]);
    lds_st(zf, B1w_o + 1536, r[3]);
    lds_st(zf, B1w_e + 2048, r[4]);
    lds_st(zf, B1w_o + 2560, r[5]);
    lds_st(zf, B1w_e + 3072, r[6]);
    lds_st(zf, B1w_o + 3584, r[7]);

    // ex1 read: addr = B1r ^ 72*m1
    float2 y[8];
#pragma unroll
    for (int m1 = 0; m1 < 8; ++m1) y[m1] = lds_ld(zf, B1r ^ (72 * m1));

    // ---- stage 2: radix-8, twiddle W64^{m2l*j1} ----
    fft8(y);
    __sincosf((float)m2l * (-6.28318530717958647693f / 64.f), &sn, &cs);
    {
      float2 w1 = make_float2(cs, sn);
      float2 w2 = cmul(w1, w1);
      float2 w3 = cmul(w2, w1);
      float2 w4 = cmul(w2, w2);
      y[1] = cmul(y[1], w1);
      y[2] = cmul(y[2], w2);
      y[3] = cmul(y[3], w3);
      y[4] = cmul(y[4], w4);
      y[5] = cmul(y[5], cmul(w4, w1));
      y[6] = cmul(y[6], cmul(w4, w2));
      y[7] = cmul(y[7], cmul(w4, w3));
    }
    // ex2 write: same 8 addresses as ex1 read (in-place along m1/j1)
#pragma unroll
    for (int j1 = 0; j1 < 8; ++j1) lds_st(zf, B1r ^ (72 * j1), y[j1]);

    // ex2 read: addr = B2r ^ (m<<3)
    float2 h[8];
#pragma unroll
    for (int m = 0; m < 8; ++m) h[m] = lds_ld(zf, B2r ^ (m << 3));

    // ---- stage 3 + natural-order store: addr = base_even/odd + j2*512 ----
    fft8(h);
    lds_st(zf, B3_e,        h[0]);
    lds_st(zf, B3_o +  512, h[1]);
    lds_st(zf, B3_e + 1024, h[2]);
    lds_st(zf, B3_o + 1536, h[3]);
    lds_st(zf, B3_e + 2048, h[4]);
    lds_st(zf, B3_o + 2560, h[5]);
    lds_st(zf, B3_e + 3072, h[6]);
    lds_st(zf, B3_o + 3584, h[7]);
  }
  __syncthreads();

  // -------- unpack via conjugate symmetry + transposed coalesced write -----
  {
    const int f  = t & 15;   // frame-in-tile (lane-fastest -> 64B segments)
    const int q  = t >> 4;   // bin residue 0..63
    const int fr = f0 + f;
    const float2* zq = z + (f << 9);
    const int G    = ((q >> 3) << 3) | ((q & 7) ^ (q >> 3));
    const int BK_e = (G ^ f) << 3;     // Zk read, even i
    const int BK_o = BK_e ^ 64;        //          odd i
    float* out_r = out;
    float* out_i = out + (size_t)16 * NBINS * NFRAMES;
    float sn, cs;
    __sincosf((float)q * (-6.28318530717958647693f / 1024.f), &sn, &cs);
    float2 tw = make_float2(cs, sn);
    // bin step 64: stp = W_1024^64 = e^{-i*pi/8}
    const float2 stp = make_float2(0.92387953251128675613f, -0.38268343236508977173f);
#pragma unroll
    for (int i = 0; i < 5; ++i) {
      int k = q + (i << 6);
      if (k > 256) break;
      float2 Zk = lds_ld(zq, ((i & 1) ? BK_o : BK_e) + i * 512);
      int mk = (512 - k) & 511;
      float2 Zm = lds_ld(zq, (swz(mk) ^ f) << 3);
      float xer  = 0.5f * (Zk.x + Zm.x);
      float xei  = 0.5f * (Zk.y - Zm.y);
      float xor_ = 0.5f * (Zk.y + Zm.y);
      float xoi  = -0.5f * (Zk.x - Zm.x);
      float ur = tw.x * xor_ - tw.y * xoi;
      float ui = tw.x * xoi + tw.y * xor_;
      size_t o1 = ((size_t)b * NBINS + k) * NFRAMES + fr;
      size_t o2 = ((size_t)b * NBINS + (512 - k)) * NFRAMES + fr;
      out_r[o1] = xer + ur;
      out_i[o1] = xei + ui;
      out_r[o2] = xer - ur;
      out_i[o2] = ui - xei;
      tw = cmul(tw, stp);
    }
  }
}

extern "C" void kernel_launch(void* const* d_in, const int* in_sizes, int n_in,
                              void* d_out, int out_size, void* d_ws, size_t ws_size,
                              hipStream_t stream) {
  const float* x = (const float*)d_in[0];
  const float* w = (const float*)d_in[1];
  float* out = (float*)d_out;
  (void)in_sizes; (void)n_in; (void)out_size; (void)d_ws; (void)ws_size;
  stft_kernel<<<dim3(1024), dim3(1024), 0, stream>>>(x, w, out);
}